// Round 1
// baseline (328.629 us; speedup 1.0000x reference)
//
#include <hip/hip_runtime.h>
#include <hip/hip_fp16.h>

#define CH 256
#define HH 96
#define WW 160
#define HW (HH * WW) // 15360

typedef _Float16 h4 __attribute__((ext_vector_type(4)));
typedef float f32x4 __attribute__((ext_vector_type(4)));

__device__ inline unsigned pk2f(float a, float b) {
    return (unsigned)__half_as_ushort(__float2half(a)) |
           ((unsigned)__half_as_ushort(__float2half(b)) << 16);
}

// v5: occupancy push. 16-channel chunks (raw prefetch regs 56 -> 28) so
// total VGPR+AGPR fits 128 -> 4 waves/SIMD (was 3 @ ~156 regs). LDS is
// double-buffered (2 x 12.25 KB = same 24.5 KB as v4) giving ONE barrier
// per chunk instead of two. Iteration order: MFMA(buf[ch]) first, then
// commit(ch+1) -> other buffer (vmcnt wait lands after MFMAs are issued),
// then issue loads for ch+2, then the single barrier. MFMA drops to
// v_mfma_f32_16x16x16_f16 (K=16): A/B = 4 halves (k = (lane>>4)*4 + i),
// C/D layout identical to the x32 shape, so the epilogue is unchanged.
__global__ __launch_bounds__(256, 4)
void corr_v5(const float* __restrict__ Fp, const float* __restrict__ Sp,
             float* __restrict__ out) {
    // [buf2][row12][jt2][qq4][n16] : uint2 = 4 halves = 4 channels of group qq
    __shared__ uint2 sS[2 * 12 * 128]; // 24576 B

    const int bid = blockIdx.x;
    const int b   = bid & 7;       // batch-per-XCD swizzle (XCD L2 holds one batch)
    const int rem = bid >> 3;      // 0..239
    const int y0  = (rem / 10) * 4;
    const int x0  = (rem % 10) * 16;

    const int t    = threadIdx.x;
    const int lane = t & 63;
    const int wv   = t >> 6;
    const int q    = lane >> 4;
    const int n    = lane & 15;

    const float*  Fb  = Fp + (size_t)b * CH * HW;
    const float2* Sb2 = (const float2*)(Sp + (size_t)b * CH * HW);

    // ---- staging lane map (unchanged from v4): (np, qq, jt)
    const int np = lane & 7;
    const int qq = (lane >> 3) & 3;
    const int jt = (lane >> 5) & 1;
    const int gx = x0 - 4 + jt * 16 + np * 2;
    const bool xok = (gx >= 0) & (gx + 1 < WW);

    bool okv[3];
    int  sOff[3]; // float2-offsets from Sb2 (32-bit, lets compiler use saddr form)
#pragma unroll
    for (int i = 0; i < 3; i++) {
        const int row = i * 4 + wv;
        const int gy  = y0 - 4 + row;
        okv[i] = ((unsigned)gy < HH) & xok;
        sOff[i] = okv[i] ? (qq * 4) * (HW / 2) + gy * (WW / 2) + (gx >> 1) : 0;
    }
    int fOff = (q * 4) * HW + (y0 + wv) * WW + x0 + n;

    // ---- raw prefetch registers: 24 + 4 VGPRs (was 48 + 8)
    float2 rawS[3][4];
    float  rawF[4];
    h4     av;

    auto load_raw = [&]() {
#pragma unroll
        for (int i = 0; i < 3; i++)
#pragma unroll
            for (int j = 0; j < 4; j++)
                rawS[i][j] = Sb2[sOff[i] + j * (HW / 2)];
#pragma unroll
        for (int j = 0; j < 4; j++)
            rawF[j] = Fb[fOff + j * HW];
#pragma unroll
        for (int i = 0; i < 3; i++) sOff[i] += 8 * HW;  // +16 planes (float2 units)
        fOff += 16 * HW;
    };

    const int wrow = jt * 64 + qq * 16 + np * 2;

    auto commit = [&](int wb) {
        // A fragment for the chunk being committed (consumed NEXT iteration;
        // the MFMAs of the current chunk already read the old av above).
        h4 a;
#pragma unroll
        for (int j = 0; j < 4; j++) a[j] = (_Float16)rawF[j];
        av = a;
#pragma unroll
        for (int i = 0; i < 3; i++) {
            float ax[4], ay[4];
#pragma unroll
            for (int j = 0; j < 4; j++) {
                ax[j] = okv[i] ? rawS[i][j].x : 0.0f;
                ay[j] = okv[i] ? rawS[i][j].y : 0.0f;
            }
            uint4 v;
            v.x = pk2f(ax[0], ax[1]);  // col gx   : channels 0..3 of group qq
            v.y = pk2f(ax[2], ax[3]);
            v.z = pk2f(ay[0], ay[1]);  // col gx+1
            v.w = pk2f(ay[2], ay[3]);
            *(uint4*)&sS[wb + (i * 4 + wv) * 128 + wrow] = v;
        }
    };

    f32x4 acc[9][2];
#pragma unroll
    for (int dy = 0; dy < 9; dy++) {
        f32x4 z = {0.f, 0.f, 0.f, 0.f};
        acc[dy][0] = z;
        acc[dy][1] = z;
    }

    // ---- prologue: chunk 0 staged to buf0, chunk 1 in flight
    load_raw();
    commit(0);
    load_raw();
    __syncthreads();

#pragma unroll 1
    for (int ch = 0; ch < 16; ch++) {
        const int rb = (ch & 1) ? 1536 : 0;
        const uint2* rp = sS + rb + wv * 128 + q * 16 + n;

        // ---- MFMA on chunk ch (issued before the commit's vmcnt stall)
#pragma unroll
        for (int dy = 0; dy < 9; dy++) {
            h4 b0 = *(const h4*)(rp + dy * 128);        // jt = 0
            h4 b1 = *(const h4*)(rp + dy * 128 + 64);   // jt = 1
            acc[dy][0] = __builtin_amdgcn_mfma_f32_16x16x16f16(av, b0, acc[dy][0], 0, 0, 0);
            acc[dy][1] = __builtin_amdgcn_mfma_f32_16x16x16f16(av, b1, acc[dy][1], 0, 0, 0);
        }

        if (ch < 15) {
            commit(1536 - rb);        // chunk ch+1 -> other buffer
            if (ch < 14) load_raw();  // chunk ch+2 in flight across the barrier
            __syncthreads();          // single barrier per chunk
        }
    }

    // ---- epilogue: D row m=q*4+r, col n; dx+4 = jt*16 + n - m in [0,8].
    const int y = y0 + wv;
#pragma unroll
    for (int r = 0; r < 4; r++) {
        const int m = q * 4 + r;
#pragma unroll
        for (int jtt = 0; jtt < 2; jtt++) {
            const int dxp = jtt * 16 + n - m;
            if (dxp >= 0 && dxp <= 8) {
                float* p = out + ((size_t)(b * 81 + dxp) * HH + y) * WW + x0 + m;
#pragma unroll
                for (int dy = 0; dy < 9; dy++) {
                    p[(size_t)dy * 9 * HW] = acc[dy][jtt][r] * (1.0f / 256.0f);
                }
            }
        }
    }
}

extern "C" void kernel_launch(void* const* d_in, const int* in_sizes, int n_in,
                              void* d_out, int out_size, void* d_ws, size_t ws_size,
                              hipStream_t stream) {
    const float* F = (const float*)d_in[0];
    const float* S = (const float*)d_in[1];
    float* o = (float*)d_out;
    corr_v5<<<dim3(1920), dim3(256), 0, stream>>>(F, S, o);
}